// Round 1
// baseline (588.661 us; speedup 1.0000x reference)
//
#include <hip/hip_runtime.h>
#include <stdint.h>

// ---------- types ----------
typedef __bf16 bf16x8 __attribute__((ext_vector_type(8)));
typedef float  f32x4  __attribute__((ext_vector_type(4)));

#define DEV __device__ __forceinline__

DEV ushort f2bf(float f) {               // RTNE float -> bf16 bits
  union { float f; uint32_t u; } v; v.f = f;
  uint32_t u = v.u;
  return (ushort)((u + 0x7fffu + ((u >> 16) & 1u)) >> 16);
}
DEV float bf2f(uint32_t bits) {
  union { uint32_t u; float f; } v; v.u = bits << 16;
  return v.f;
}

// async global->LDS, 16B per lane. LDS dest must be wave-uniform base + lane*16.
DEV void async16(const void* g, void* l) {
  __builtin_amdgcn_global_load_lds(
      (__attribute__((address_space(1))) void*)(uintptr_t)g,
      (__attribute__((address_space(3))) void*)(uint32_t)(uintptr_t)l,
      16, 0, 0);
}

// ---------- kernel 1: mod = t @ mod_w.T  (16 x 2048, K=1024, fp32) ----------
__global__ __launch_bounds__(64)
void mod_gemm_kernel(const float* __restrict__ t, const float* __restrict__ w,
                     float* __restrict__ mod) {
  int j = blockIdx.x;          // 0..2047
  int lane = threadIdx.x;      // 0..63
  float wr[16];
#pragma unroll
  for (int i = 0; i < 16; ++i) wr[i] = w[(size_t)j * 1024 + lane + i * 64];
  for (int b = 0; b < 16; ++b) {
    float s = 0.f;
#pragma unroll
    for (int i = 0; i < 16; ++i) s += wr[i] * t[b * 1024 + lane + i * 64];
#pragma unroll
    for (int m = 32; m >= 1; m >>= 1) s += __shfl_xor(s, m, 64);
    if (lane == 0) mod[b * 2048 + j] = s;
  }
}

// ---------- kernel 2: RMSNorm + modulate -> bf16 h  (16384 rows x 1024) ----------
__global__ __launch_bounds__(256)
void rms_mod_kernel(const float* __restrict__ x, const float* __restrict__ nw,
                    const float* __restrict__ mod, ushort* __restrict__ h) {
  int row = blockIdx.x;        // b*1024 + n
  int b = row >> 10;
  int tid = threadIdx.x;
  const float4 xv = *(const float4*)(x + (size_t)row * 1024 + tid * 4);
  float ss = xv.x * xv.x + xv.y * xv.y + xv.z * xv.z + xv.w * xv.w;
#pragma unroll
  for (int m = 32; m >= 1; m >>= 1) ss += __shfl_xor(ss, m, 64);
  __shared__ float red[4];
  int w = tid >> 6, lane = tid & 63;
  if (lane == 0) red[w] = ss;
  __syncthreads();
  float tot = red[0] + red[1] + red[2] + red[3];
  float rn = rsqrtf(tot * (1.f / 1024.f) + 1e-6f);
  float4 wv = *(const float4*)(nw + tid * 4);
  float4 sc = *(const float4*)(mod + (size_t)b * 2048 + tid * 4);
  float4 sh = *(const float4*)(mod + (size_t)b * 2048 + 1024 + tid * 4);
  ushort4 o;
  o.x = f2bf(xv.x * rn * wv.x * (1.f + sc.x) + sh.x);
  o.y = f2bf(xv.y * rn * wv.y * (1.f + sc.y) + sh.y);
  o.z = f2bf(xv.z * rn * wv.z * (1.f + sc.z) + sh.z);
  o.w = f2bf(xv.w * rn * wv.w * (1.f + sc.w) + sh.w);
  *(ushort4*)(h + (size_t)row * 1024 + tid * 4) = o;
}

// ---------- kernel 3: fp32 -> bf16 cast (vectorized by 4) ----------
__global__ __launch_bounds__(256)
void cvt_bf16_kernel(const float* __restrict__ in, ushort* __restrict__ out, int n4) {
  int i = blockIdx.x * 256 + threadIdx.x;
  if (i < n4) {
    float4 v = ((const float4*)in)[i];
    ushort4 o;
    o.x = f2bf(v.x); o.y = f2bf(v.y); o.z = f2bf(v.z); o.w = f2bf(v.w);
    ((ushort4*)out)[i] = o;
  }
}

// ---------- GEMM: C[M][N] = A[M][K] * B[N][K]^T, bf16 in, 128x128 tile ----------
// LDS layout: tile[row][cslot] where cslot = chunk ^ ((row>>1)&3), chunk = 8 bf16 (16B).
// Gives 2-way (free) bank aliasing on ds_read_b128 and 64B-contiguous global loads.
template <int NCOLS, bool QKV>
__global__ __launch_bounds__(256, 3)
void gemm_bt_kernel(const ushort* __restrict__ A, const ushort* __restrict__ B,
                    float* __restrict__ outf,
                    ushort* __restrict__ qb, ushort* __restrict__ kb,
                    ushort* __restrict__ vtb) {
  __shared__ ushort As[512 * 8];   // 128 rows x 4 chunks x 8  (8 KB)
  __shared__ ushort Bs[512 * 8];
  const int K = 1024;
  const int m0 = blockIdx.y * 128, n0 = blockIdx.x * 128;
  const int tid = threadIdx.x;
  const int w = tid >> 6, lane = tid & 63, quad = lane >> 4, l15 = lane & 15;
  const int wm = (w >> 1) * 64, wn = (w & 1) * 64;
  const f32x4 fzero = {0.f, 0.f, 0.f, 0.f};
  f32x4 acc[4][4];
#pragma unroll
  for (int a = 0; a < 4; ++a)
#pragma unroll
    for (int b = 0; b < 4; ++b) acc[a][b] = fzero;

  const int s0 = tid, s1 = 256 + tid;
  const int r0 = s0 >> 2, c0 = (s0 & 3) ^ ((r0 >> 1) & 3);
  const int r1 = s1 >> 2, c1 = (s1 & 3) ^ ((r1 >> 1) & 3);
  const ushort* Ag0 = A + (size_t)(m0 + r0) * K + c0 * 8;
  const ushort* Ag1 = A + (size_t)(m0 + r1) * K + c1 * 8;
  const ushort* Bg0 = B + (size_t)(n0 + r0) * K + c0 * 8;
  const ushort* Bg1 = B + (size_t)(n0 + r1) * K + c1 * 8;

  for (int kt = 0; kt < K; kt += 32) {
    async16(Ag0 + kt, As + s0 * 8);
    async16(Ag1 + kt, As + s1 * 8);
    async16(Bg0 + kt, Bs + s0 * 8);
    async16(Bg1 + kt, Bs + s1 * 8);
    __syncthreads();
    bf16x8 af[4], bfr[4];
#pragma unroll
    for (int tm = 0; tm < 4; ++tm) {
      int r = wm + tm * 16 + l15;
      int cs = quad ^ ((r >> 1) & 3);
      af[tm] = *(const bf16x8*)(As + (r * 4 + cs) * 8);
    }
#pragma unroll
    for (int tn = 0; tn < 4; ++tn) {
      int r = wn + tn * 16 + l15;
      int cs = quad ^ ((r >> 1) & 3);
      bfr[tn] = *(const bf16x8*)(Bs + (r * 4 + cs) * 8);
    }
#pragma unroll
    for (int tm = 0; tm < 4; ++tm)
#pragma unroll
      for (int tn = 0; tn < 4; ++tn)
        acc[tm][tn] = __builtin_amdgcn_mfma_f32_16x16x32_bf16(af[tm], bfr[tn],
                                                              acc[tm][tn], 0, 0, 0);
    __syncthreads();
  }

  // Epilogue. C/D layout: col = lane&15, row = quad*4 + reg  [m89-verified]
  if (!QKV) {
#pragma unroll
    for (int tm = 0; tm < 4; ++tm)
#pragma unroll
      for (int tn = 0; tn < 4; ++tn) {
        int col = n0 + wn + tn * 16 + l15;
#pragma unroll
        for (int r = 0; r < 4; ++r) {
          int row = m0 + wm + tm * 16 + quad * 4 + r;
          outf[(size_t)row * NCOLS + col] = acc[tm][tn][r];
        }
      }
  } else {
    // col j in [0,3072): head = j/192, part = (j%192)/64 (0:q 1:k 2:v), d = j%64
#pragma unroll
    for (int tm = 0; tm < 4; ++tm)
#pragma unroll
      for (int tn = 0; tn < 4; ++tn) {
        int col = n0 + wn + tn * 16 + l15;
        uint32_t hd = (uint32_t)col / 192u;
        uint32_t rem = (uint32_t)col - hd * 192u;
        int part = rem >> 6, d = rem & 63;
#pragma unroll
        for (int r = 0; r < 4; ++r) {
          int row = m0 + wm + tm * 16 + quad * 4 + r;
          int b = row >> 10, n = row & 1023;
          size_t bh = (size_t)b * 16 + hd;
          ushort v = f2bf(acc[tm][tn][r]);
          if (part == 0)      qb[(bh * 1024 + n) * 64 + d] = v;
          else if (part == 1) kb[(bh * 1024 + n) * 64 + d] = v;
          else                vtb[(bh * 64 + d) * 1024 + n] = v;  // V stored transposed
        }
      }
  }
}

// ---------- kernel 5: 2D RoPE in-place on q (with 1/8 scale) and k ----------
__global__ __launch_bounds__(256)
void rope_kernel(ushort* __restrict__ qb, ushort* __restrict__ kb) {
  size_t idx = (size_t)blockIdx.x * 256 + threadIdx.x;  // 0 .. 256*1024*32-1
  int p = (int)(idx & 31);            // pair index 0..31
  size_t rowi = idx >> 5;             // bh*1024 + n
  int n = (int)(rowi & 1023);
  int j = p & 15;
  float pos = (p < 16) ? (float)(n & 31) : (float)(n >> 5);
  float theta = __powf(10000.f, -(float)j * (1.f / 16.f));
  float ang = pos * theta;
  float sn, cs;
  __sincosf(ang, &sn, &cs);
  size_t a = rowi * 64 + (size_t)p * 2;
  uint32_t qu = *(uint32_t*)(qb + a);
  float x0 = bf2f(qu & 0xffffu), x1 = bf2f(qu >> 16);
  float y0 = (x0 * cs - x1 * sn) * 0.125f;   // fold attn scale into q
  float y1 = (x1 * cs + x0 * sn) * 0.125f;
  *(uint32_t*)(qb + a) = (uint32_t)f2bf(y0) | ((uint32_t)f2bf(y1) << 16);
  uint32_t ku = *(uint32_t*)(kb + a);
  float k0 = bf2f(ku & 0xffffu), k1 = bf2f(ku >> 16);
  float z0 = k0 * cs - k1 * sn;
  float z1 = k1 * cs + k0 * sn;
  *(uint32_t*)(kb + a) = (uint32_t)f2bf(z0) | ((uint32_t)f2bf(z1) << 16);
}

// ---------- kernel 6: flash attention, 128-row Q block, 8 K/V tiles of 128 ----------
// LDS 64KB total: Ks (also Q staging) 16KB + Vs 16KB + Ps 32KB  -> 2 blocks/CU
__global__ __launch_bounds__(256, 2)
void attn_kernel(const ushort* __restrict__ qbuf, const ushort* __restrict__ kbuf,
                 const ushort* __restrict__ vtbuf, ushort* __restrict__ aout) {
  __shared__ ushort Ks[128 * 8 * 8];   // [row][cslot(8)][8], cslot = c ^ (row&7)
  __shared__ ushort Vs[64 * 16 * 8];   // V^T: [d][cslot(16)][8], cslot=(c&8)|((c&7)^(d&7))
  __shared__ ushort Ps[128 * 16 * 8];  // P round-trip, same swizzle as Vs rows

  const int bh = blockIdx.y;
  const int q0 = blockIdx.x * 128;
  const ushort* Qg = qbuf + (size_t)bh * 1024 * 64;
  const ushort* Kg = kbuf + (size_t)bh * 1024 * 64;
  const ushort* Vg = vtbuf + (size_t)bh * 64 * 1024;
  const int tid = threadIdx.x;
  const int w = tid >> 6, lane = tid & 63, quad = lane >> 4, l15 = lane & 15;
  const f32x4 fzero = {0.f, 0.f, 0.f, 0.f};

  // stage Q into Ks, pull fragments to registers (constant across k-tiles)
#pragma unroll
  for (int i = 0; i < 4; ++i) {
    int s = i * 256 + tid, r = s >> 3, c = (s & 7) ^ (r & 7);
    async16(Qg + (size_t)(q0 + r) * 64 + c * 8, Ks + s * 8);
  }
  __syncthreads();
  bf16x8 aq[2][2];
#pragma unroll
  for (int tm = 0; tm < 2; ++tm)
#pragma unroll
    for (int ks = 0; ks < 2; ++ks) {
      int r = w * 32 + tm * 16 + l15;
      int cs = (ks * 4 + quad) ^ (r & 7);
      aq[tm][ks] = *(const bf16x8*)(Ks + (r * 8 + cs) * 8);
    }
  __syncthreads();  // everyone done reading Q before Ks is reused for K tiles

  float mrun[2][4], lrun[2][4];
  f32x4 oacc[2][4];
#pragma unroll
  for (int tm = 0; tm < 2; ++tm)
#pragma unroll
    for (int r = 0; r < 4; ++r) { mrun[tm][r] = -1e30f; lrun[tm][r] = 0.f; }
#pragma unroll
  for (int tm = 0; tm < 2; ++tm)
#pragma unroll
    for (int td = 0; td < 4; ++td) oacc[tm][td] = fzero;

  for (int kt = 0; kt < 1024; kt += 128) {
#pragma unroll
    for (int i = 0; i < 4; ++i) {   // K tile
      int s = i * 256 + tid, r = s >> 3, c = (s & 7) ^ (r & 7);
      async16(Kg + (size_t)(kt + r) * 64 + c * 8, Ks + s * 8);
    }
#pragma unroll
    for (int i = 0; i < 4; ++i) {   // V^T tile
      int s = i * 256 + tid, d = s >> 4, cs = s & 15;
      int c = (cs & 8) | ((cs & 7) ^ (d & 7));
      async16(Vg + (size_t)d * 1024 + kt + c * 8, Vs + s * 8);
    }
    __syncthreads();

    // S = Q K^T  (each wave owns 32 rows)
    f32x4 sacc[2][8];
#pragma unroll
    for (int tm = 0; tm < 2; ++tm)
#pragma unroll
      for (int tn = 0; tn < 8; ++tn) sacc[tm][tn] = fzero;
#pragma unroll
    for (int ks = 0; ks < 2; ++ks) {
#pragma unroll
      for (int tn = 0; tn < 8; ++tn) {
        int r = tn * 16 + l15;
        int cs = (ks * 4 + quad) ^ (r & 7);
        bf16x8 bk = *(const bf16x8*)(Ks + (r * 8 + cs) * 8);
        sacc[0][tn] = __builtin_amdgcn_mfma_f32_16x16x32_bf16(aq[0][ks], bk, sacc[0][tn], 0, 0, 0);
        sacc[1][tn] = __builtin_amdgcn_mfma_f32_16x16x32_bf16(aq[1][ks], bk, sacc[1][tn], 0, 0, 0);
      }
    }

    // online softmax; write P (bf16) into Ps with A-operand-friendly swizzle
#pragma unroll
    for (int tm = 0; tm < 2; ++tm) {
#pragma unroll
      for (int r = 0; r < 4; ++r) {
        float mx = sacc[tm][0][r];
#pragma unroll
        for (int tn = 1; tn < 8; ++tn) mx = fmaxf(mx, sacc[tm][tn][r]);
#pragma unroll
        for (int m = 8; m >= 1; m >>= 1) mx = fmaxf(mx, __shfl_xor(mx, m, 64));
        float mold = mrun[tm][r];
        float mnew = fmaxf(mold, mx);
        float alpha = __expf(mold - mnew);
        mrun[tm][r] = mnew;
        int row = w * 32 + tm * 16 + quad * 4 + r;
        float rs = 0.f;
#pragma unroll
        for (int tn = 0; tn < 8; ++tn) {
          float p = __expf(sacc[tm][tn][r] - mnew);
          rs += p;
          int colc = tn * 2 + (l15 >> 3);
          int cs = (colc & 8) | ((colc & 7) ^ (row & 7));
          Ps[(row * 16 + cs) * 8 + (l15 & 7)] = f2bf(p);
        }
#pragma unroll
        for (int m = 8; m >= 1; m >>= 1) rs += __shfl_xor(rs, m, 64);
        lrun[tm][r] = lrun[tm][r] * alpha + rs;
#pragma unroll
        for (int td = 0; td < 4; ++td) oacc[tm][td][r] *= alpha;
      }
    }

    // O += P @ V   (P rows are wave-private: no barrier needed, only lgkmcnt)
#pragma unroll
    for (int ks = 0; ks < 4; ++ks) {
      bf16x8 ap[2];
#pragma unroll
      for (int tm = 0; tm < 2; ++tm) {
        int row = w * 32 + tm * 16 + l15;
        int c = ks * 4 + quad;
        int cs = (c & 8) | ((c & 7) ^ (row & 7));
        ap[tm] = *(const bf16x8*)(Ps + (row * 16 + cs) * 8);
      }
#pragma unroll
      for (int td = 0; td < 4; ++td) {
        int dr = td * 16 + l15;
        int c = ks * 4 + quad;
        int cs = (c & 8) | ((c & 7) ^ (dr & 7));
        bf16x8 bv = *(const bf16x8*)(Vs + (dr * 16 + cs) * 8);
        oacc[0][td] = __builtin_amdgcn_mfma_f32_16x16x32_bf16(ap[0], bv, oacc[0][td], 0, 0, 0);
        oacc[1][td] = __builtin_amdgcn_mfma_f32_16x16x32_bf16(ap[1], bv, oacc[1][td], 0, 0, 0);
      }
    }
    __syncthreads();
  }

  // epilogue: O /= l, write to [b][n][h*64+d] bf16 (A-matrix for WO GEMM)
  const int b = bh >> 4, hh = bh & 15;
#pragma unroll
  for (int tm = 0; tm < 2; ++tm)
#pragma unroll
    for (int td = 0; td < 4; ++td)
#pragma unroll
      for (int r = 0; r < 4; ++r) {
        int n = q0 + w * 32 + tm * 16 + quad * 4 + r;
        int d = td * 16 + l15;
        float o = oacc[tm][td][r] / lrun[tm][r];
        aout[((size_t)b * 1024 + n) * 1024 + hh * 64 + d] = f2bf(o);
      }
}

// ---------- launch ----------
extern "C" void kernel_launch(void* const* d_in, const int* in_sizes, int n_in,
                              void* d_out, int out_size, void* d_ws, size_t ws_size,
                              hipStream_t stream) {
  const float* x    = (const float*)d_in[0];
  const float* t    = (const float*)d_in[1];
  const float* nw   = (const float*)d_in[2];
  const float* mw   = (const float*)d_in[3];
  const float* qkvw = (const float*)d_in[4];
  const float* wow  = (const float*)d_in[5];
  float* out = (float*)d_out;
  char* ws = (char*)d_ws;

  // workspace map (≈176 MB total)
  float*  modbuf  = (float*)(ws);                    // 16*2048*4        = 131072
  ushort* hbuf    = (ushort*)(ws + 131072);          // 16384*1024*2     = 33554432
  ushort* qkvw_b  = (ushort*)(ws + 33685504);        // 3072*1024*2      = 6291456
  ushort* wow_b   = (ushort*)(ws + 39976960);        // 1024*1024*2      = 2097152
  ushort* qbuf    = (ushort*)(ws + 42074112);        // 256*1024*64*2    = 33554432
  ushort* kbuf    = (ushort*)(ws + 75628544);        // 33554432
  ushort* vtbuf   = (ushort*)(ws + 109182976);       // 33554432 (V transposed)
  ushort* abuf    = (ushort*)(ws + 142737408);       // 33554432 (attn out)

  mod_gemm_kernel<<<dim3(2048), dim3(64), 0, stream>>>(t, mw, modbuf);
  rms_mod_kernel<<<dim3(16384), dim3(256), 0, stream>>>(x, nw, modbuf, hbuf);
  cvt_bf16_kernel<<<dim3(3072), dim3(256), 0, stream>>>(qkvw, qkvw_b, 786432);
  cvt_bf16_kernel<<<dim3(1024), dim3(256), 0, stream>>>(wow, wow_b, 262144);
  gemm_bt_kernel<3072, true><<<dim3(24, 128), dim3(256), 0, stream>>>(
      hbuf, qkvw_b, nullptr, qbuf, kbuf, vtbuf);
  rope_kernel<<<dim3(32768), dim3(256), 0, stream>>>(qbuf, kbuf);
  attn_kernel<<<dim3(8, 256), dim3(256), 0, stream>>>(qbuf, kbuf, vtbuf, abuf);
  gemm_bt_kernel<1024, false><<<dim3(8, 128), dim3(256), 0, stream>>>(
      abuf, wow_b, out, nullptr, nullptr, nullptr);
}

// Round 2
// 573.493 us; speedup vs baseline: 1.0264x; 1.0264x over previous
//
#include <hip/hip_runtime.h>
#include <stdint.h>

// ---------- types ----------
typedef __bf16    bf16x8 __attribute__((ext_vector_type(8)));
typedef float     f32x4  __attribute__((ext_vector_type(4)));
typedef _Float16  f16;
typedef _Float16  f16x4  __attribute__((ext_vector_type(4)));

#define DEV __device__ __forceinline__

DEV ushort f2bf(float f) {               // RTNE float -> bf16 bits
  union { float f; uint32_t u; } v; v.f = f;
  uint32_t u = v.u;
  return (ushort)((u + 0x7fffu + ((u >> 16) & 1u)) >> 16);
}

// async global->LDS, 16B per lane. LDS dest must be wave-uniform base + lane*16.
DEV void async16(const void* g, void* l) {
  __builtin_amdgcn_global_load_lds(
      (__attribute__((address_space(1))) void*)(uintptr_t)g,
      (__attribute__((address_space(3))) void*)(uint32_t)(uintptr_t)l,
      16, 0, 0);
}

// ---------- kernel 1: mod = t @ mod_w.T  (16 x 2048, K=1024, fp32) ----------
__global__ __launch_bounds__(64)
void mod_gemm_kernel(const float* __restrict__ t, const float* __restrict__ w,
                     float* __restrict__ mod) {
  int j = blockIdx.x;
  int lane = threadIdx.x;
  float wr[16];
#pragma unroll
  for (int i = 0; i < 16; ++i) wr[i] = w[(size_t)j * 1024 + lane + i * 64];
  for (int b = 0; b < 16; ++b) {
    float s = 0.f;
#pragma unroll
    for (int i = 0; i < 16; ++i) s += wr[i] * t[b * 1024 + lane + i * 64];
#pragma unroll
    for (int m = 32; m >= 1; m >>= 1) s += __shfl_xor(s, m, 64);
    if (lane == 0) mod[b * 2048 + j] = s;
  }
}

// ---------- kernel 2: RMSNorm + modulate -> bf16 h ----------
__global__ __launch_bounds__(256)
void rms_mod_kernel(const float* __restrict__ x, const float* __restrict__ nw,
                    const float* __restrict__ mod, ushort* __restrict__ h) {
  int row = blockIdx.x;
  int b = row >> 10;
  int tid = threadIdx.x;
  const float4 xv = *(const float4*)(x + (size_t)row * 1024 + tid * 4);
  float ss = xv.x * xv.x + xv.y * xv.y + xv.z * xv.z + xv.w * xv.w;
#pragma unroll
  for (int m = 32; m >= 1; m >>= 1) ss += __shfl_xor(ss, m, 64);
  __shared__ float red[4];
  int w = tid >> 6, lane = tid & 63;
  if (lane == 0) red[w] = ss;
  __syncthreads();
  float tot = red[0] + red[1] + red[2] + red[3];
  float rn = rsqrtf(tot * (1.f / 1024.f) + 1e-6f);
  float4 wv = *(const float4*)(nw + tid * 4);
  float4 sc = *(const float4*)(mod + (size_t)b * 2048 + tid * 4);
  float4 sh = *(const float4*)(mod + (size_t)b * 2048 + 1024 + tid * 4);
  ushort4 o;
  o.x = f2bf(xv.x * rn * wv.x * (1.f + sc.x) + sh.x);
  o.y = f2bf(xv.y * rn * wv.y * (1.f + sc.y) + sh.y);
  o.z = f2bf(xv.z * rn * wv.z * (1.f + sc.z) + sh.z);
  o.w = f2bf(xv.w * rn * wv.w * (1.f + sc.w) + sh.w);
  *(ushort4*)(h + (size_t)row * 1024 + tid * 4) = o;
}

// ---------- kernel 3: fp32 -> bf16 cast ----------
__global__ __launch_bounds__(256)
void cvt_bf16_kernel(const float* __restrict__ in, ushort* __restrict__ out, int n4) {
  int i = blockIdx.x * 256 + threadIdx.x;
  if (i < n4) {
    float4 v = ((const float4*)in)[i];
    ushort4 o;
    o.x = f2bf(v.x); o.y = f2bf(v.y); o.z = f2bf(v.z); o.w = f2bf(v.w);
    ((ushort4*)out)[i] = o;
  }
}

// ---------- GEMM: C[M][N] = A[M][K] * B[N][K]^T, bf16 in, 128x128 tile ----------
template <int NCOLS, bool QKV>
__global__ __launch_bounds__(256, 3)
void gemm_bt_kernel(const ushort* __restrict__ A, const ushort* __restrict__ B,
                    float* __restrict__ outf,
                    f16* __restrict__ qb, f16* __restrict__ kb,
                    f16* __restrict__ vtb) {
  __shared__ ushort As[512 * 8];
  __shared__ ushort Bs[512 * 8];
  const int K = 1024;
  const int m0 = blockIdx.y * 128, n0 = blockIdx.x * 128;
  const int tid = threadIdx.x;
  const int w = tid >> 6, lane = tid & 63, quad = lane >> 4, l15 = lane & 15;
  const int wm = (w >> 1) * 64, wn = (w & 1) * 64;
  const f32x4 fzero = {0.f, 0.f, 0.f, 0.f};
  f32x4 acc[4][4];
#pragma unroll
  for (int a = 0; a < 4; ++a)
#pragma unroll
    for (int b = 0; b < 4; ++b) acc[a][b] = fzero;

  const int s0 = tid, s1 = 256 + tid;
  const int r0 = s0 >> 2, c0 = (s0 & 3) ^ ((r0 >> 1) & 3);
  const int r1 = s1 >> 2, c1 = (s1 & 3) ^ ((r1 >> 1) & 3);
  const ushort* Ag0 = A + (size_t)(m0 + r0) * K + c0 * 8;
  const ushort* Ag1 = A + (size_t)(m0 + r1) * K + c1 * 8;
  const ushort* Bg0 = B + (size_t)(n0 + r0) * K + c0 * 8;
  const ushort* Bg1 = B + (size_t)(n0 + r1) * K + c1 * 8;

  for (int kt = 0; kt < K; kt += 32) {
    async16(Ag0 + kt, As + s0 * 8);
    async16(Ag1 + kt, As + s1 * 8);
    async16(Bg0 + kt, Bs + s0 * 8);
    async16(Bg1 + kt, Bs + s1 * 8);
    __syncthreads();
    bf16x8 af[4], bfr[4];
#pragma unroll
    for (int tm = 0; tm < 4; ++tm) {
      int r = wm + tm * 16 + l15;
      int cs = quad ^ ((r >> 1) & 3);
      af[tm] = *(const bf16x8*)(As + (r * 4 + cs) * 8);
    }
#pragma unroll
    for (int tn = 0; tn < 4; ++tn) {
      int r = wn + tn * 16 + l15;
      int cs = quad ^ ((r >> 1) & 3);
      bfr[tn] = *(const bf16x8*)(Bs + (r * 4 + cs) * 8);
    }
#pragma unroll
    for (int tm = 0; tm < 4; ++tm)
#pragma unroll
      for (int tn = 0; tn < 4; ++tn)
        acc[tm][tn] = __builtin_amdgcn_mfma_f32_16x16x32_bf16(af[tm], bfr[tn],
                                                              acc[tm][tn], 0, 0, 0);
    __syncthreads();
  }

  if (!QKV) {
#pragma unroll
    for (int tm = 0; tm < 4; ++tm)
#pragma unroll
      for (int tn = 0; tn < 4; ++tn) {
        int col = n0 + wn + tn * 16 + l15;
#pragma unroll
        for (int r = 0; r < 4; ++r) {
          int row = m0 + wm + tm * 16 + quad * 4 + r;
          outf[(size_t)row * NCOLS + col] = acc[tm][tn][r];
        }
      }
  } else {
    // col j in [0,3072): head=j/192, part=(j%192)/64, d=j%64; q/k/v stored f16
#pragma unroll
    for (int tm = 0; tm < 4; ++tm)
#pragma unroll
      for (int tn = 0; tn < 4; ++tn) {
        int col = n0 + wn + tn * 16 + l15;
        uint32_t hd = (uint32_t)col / 192u;
        uint32_t rem = (uint32_t)col - hd * 192u;
        int part = rem >> 6, d = rem & 63;
#pragma unroll
        for (int r = 0; r < 4; ++r) {
          int row = m0 + wm + tm * 16 + quad * 4 + r;
          int b = row >> 10, n = row & 1023;
          size_t bh = (size_t)b * 16 + hd;
          f16 v = (f16)acc[tm][tn][r];
          if (part == 0)      qb[(bh * 1024 + n) * 64 + d] = v;
          else if (part == 1) kb[(bh * 1024 + n) * 64 + d] = v;
          else                vtb[(bh * 64 + d) * 1024 + n] = v;  // V^T
        }
      }
  }
}

// ---------- kernel 5: 2D RoPE in-place (f16); q gets 0.125*log2(e) fold ----------
__global__ __launch_bounds__(256)
void rope_kernel(f16* __restrict__ qb, f16* __restrict__ kb) {
  size_t idx = (size_t)blockIdx.x * 256 + threadIdx.x;
  int p = (int)(idx & 31);
  size_t rowi = idx >> 5;
  int n = (int)(rowi & 1023);
  int j = p & 15;
  float pos = (p < 16) ? (float)(n & 31) : (float)(n >> 5);
  float theta = __powf(10000.f, -(float)j * (1.f / 16.f));
  float ang = pos * theta;
  float sn, cs;
  __sincosf(ang, &sn, &cs);
  const float QS = 0.125f * 1.44269504f;   // attn scale * log2(e), folded into q
  size_t a = rowi * 64 + (size_t)p * 2;
  union U { uint32_t u; f16 h[2]; };
  U qu; qu.u = *(const uint32_t*)(qb + a);
  float x0 = (float)qu.h[0], x1 = (float)qu.h[1];
  U qo;
  qo.h[0] = (f16)((x0 * cs - x1 * sn) * QS);
  qo.h[1] = (f16)((x1 * cs + x0 * sn) * QS);
  *(uint32_t*)(qb + a) = qo.u;
  U ku; ku.u = *(const uint32_t*)(kb + a);
  float k0 = (float)ku.h[0], k1 = (float)ku.h[1];
  U ko;
  ko.h[0] = (f16)(k0 * cs - k1 * sn);
  ko.h[1] = (f16)(k1 * cs + k0 * sn);
  *(uint32_t*)(kb + a) = ko.u;
}

// ---------- kernel 6: flash attention, in-register P (S^T trick), f16 MFMA ----------
// S^T = mfma(A=K, B=Q): C layout (row=k=quad*4+r, col=q=l15) == A layout of P for PV.
// LDS 32KB (K 16KB + V^T 16KB); XOR-16B swizzle -> b64 reads at 4-pass minimum.
__global__ __launch_bounds__(256, 3)
void attn_kernel(const f16* __restrict__ qbuf, const f16* __restrict__ kbuf,
                 const f16* __restrict__ vtbuf, ushort* __restrict__ aout) {
  __shared__ f16 Ks[128 * 64];   // [krow][64d], 16B col c swizzled: c^(row&7)
  __shared__ f16 Vs[64 * 128];   // V^T [d][128k], 16B col c swizzled: c^(row&15)

  const int bh = blockIdx.y;
  const int q0 = blockIdx.x * 128;
  const f16* Qg = qbuf + (size_t)bh * 1024 * 64;
  const f16* Kg = kbuf + (size_t)bh * 1024 * 64;
  const f16* Vg = vtbuf + (size_t)bh * 64 * 1024;
  const int tid = threadIdx.x;
  const int w = tid >> 6, lane = tid & 63, quad = lane >> 4, l15 = lane & 15;
  const f32x4 fzero = {0.f, 0.f, 0.f, 0.f};

  // Q B-fragments straight from global: B[n=q=l15][k=d=quad*4+i]
  f16x4 qf[2][4];
#pragma unroll
  for (int qs = 0; qs < 2; ++qs)
#pragma unroll
    for (int dc = 0; dc < 4; ++dc)
      qf[qs][dc] = *(const f16x4*)(Qg + (size_t)(q0 + w * 32 + qs * 16 + l15) * 64 +
                                   dc * 16 + quad * 4);

  f32x4 oacc[2][4];
#pragma unroll
  for (int qs = 0; qs < 2; ++qs)
#pragma unroll
    for (int ds = 0; ds < 4; ++ds) oacc[qs][ds] = fzero;
  float mrun[2] = {-1e30f, -1e30f}, lrun[2] = {0.f, 0.f};

  for (int kt = 0; kt < 1024; kt += 128) {
#pragma unroll
    for (int i = 0; i < 4; ++i) {       // K tile: 1024 16B units
      int u = i * 256 + tid, r = u >> 3, c = u & 7;
      async16(Kg + (size_t)(kt + r) * 64 + (c ^ (r & 7)) * 8, Ks + u * 8);
    }
#pragma unroll
    for (int i = 0; i < 4; ++i) {       // V^T tile
      int u = i * 256 + tid, r = u >> 4, c = u & 15;
      async16(Vg + (size_t)r * 1024 + kt + (c ^ (r & 15)) * 8, Vs + u * 8);
    }
    __syncthreads();

    // S^T: D[k=quad*4+r][q=l15], chained over d
    f32x4 sacc[2][8];
#pragma unroll
    for (int qs = 0; qs < 2; ++qs)
#pragma unroll
      for (int ks = 0; ks < 8; ++ks) sacc[qs][ks] = fzero;
#pragma unroll
    for (int ks = 0; ks < 8; ++ks) {
#pragma unroll
      for (int dc = 0; dc < 4; ++dc) {
        int row = ks * 16 + l15;
        int c16 = dc * 2 + (quad >> 1);
        f16x4 kf = *(const f16x4*)(Ks + row * 64 + ((c16 ^ (row & 7)) * 8) + (quad & 1) * 4);
        sacc[0][ks] = __builtin_amdgcn_mfma_f32_16x16x16f16(kf, qf[0][dc], sacc[0][ks], 0, 0, 0);
        sacc[1][ks] = __builtin_amdgcn_mfma_f32_16x16x16f16(kf, qf[1][dc], sacc[1][ks], 0, 0, 0);
      }
    }

    // online softmax fully in registers (lane owns q=l15; cross-quad shfl only)
    f16x4 pf[2][8];
#pragma unroll
    for (int qs = 0; qs < 2; ++qs) {
      float mx = -1e30f;
#pragma unroll
      for (int ks = 0; ks < 8; ++ks)
#pragma unroll
        for (int i = 0; i < 4; ++i) mx = fmaxf(mx, sacc[qs][ks][i]);
      mx = fmaxf(mx, __shfl_xor(mx, 16, 64));
      mx = fmaxf(mx, __shfl_xor(mx, 32, 64));
      float mnew = fmaxf(mrun[qs], mx);
      float alpha = exp2f(mrun[qs] - mnew);
      mrun[qs] = mnew;
      float rs = 0.f;
#pragma unroll
      for (int ks = 0; ks < 8; ++ks)
#pragma unroll
        for (int i = 0; i < 4; ++i) {
          float p = exp2f(sacc[qs][ks][i] - mnew);
          rs += p;
          pf[qs][ks][i] = (f16)p;
        }
      rs += __shfl_xor(rs, 16, 64);
      rs += __shfl_xor(rs, 32, 64);
      lrun[qs] = lrun[qs] * alpha + rs;
      float ar[4];
#pragma unroll
      for (int r = 0; r < 4; ++r) ar[r] = __shfl(alpha, quad * 4 + r, 64);
#pragma unroll
      for (int ds = 0; ds < 4; ++ds)
#pragma unroll
        for (int r = 0; r < 4; ++r) oacc[qs][ds][r] *= ar[r];
    }

    // O += P V : P already in A layout; V^T B-frag from LDS
#pragma unroll
    for (int ks = 0; ks < 8; ++ks) {
#pragma unroll
      for (int ds = 0; ds < 4; ++ds) {
        int row = ds * 16 + l15;
        int c16 = ks * 2 + (quad >> 1);
        f16x4 vf = *(const f16x4*)(Vs + row * 128 + ((c16 ^ (row & 15)) * 8) + (quad & 1) * 4);
        oacc[0][ds] = __builtin_amdgcn_mfma_f32_16x16x16f16(pf[0][ks], vf, oacc[0][ds], 0, 0, 0);
        oacc[1][ds] = __builtin_amdgcn_mfma_f32_16x16x16f16(pf[1][ks], vf, oacc[1][ds], 0, 0, 0);
      }
    }
    __syncthreads();
  }

  // epilogue: O /= l, write [b][n][h*64+d] bf16
  const int b = bh >> 4, hh = bh & 15;
#pragma unroll
  for (int qs = 0; qs < 2; ++qs) {
    float linv[4];
#pragma unroll
    for (int r = 0; r < 4; ++r) linv[r] = 1.f / __shfl(lrun[qs], quad * 4 + r, 64);
#pragma unroll
    for (int ds = 0; ds < 4; ++ds)
#pragma unroll
      for (int r = 0; r < 4; ++r) {
        int n = q0 + w * 32 + qs * 16 + quad * 4 + r;
        int d = ds * 16 + l15;
        aout[((size_t)b * 1024 + n) * 1024 + hh * 64 + d] = f2bf(oacc[qs][ds][r] * linv[r]);
      }
  }
}

// ---------- launch ----------
extern "C" void kernel_launch(void* const* d_in, const int* in_sizes, int n_in,
                              void* d_out, int out_size, void* d_ws, size_t ws_size,
                              hipStream_t stream) {
  const float* x    = (const float*)d_in[0];
  const float* t    = (const float*)d_in[1];
  const float* nw   = (const float*)d_in[2];
  const float* mw   = (const float*)d_in[3];
  const float* qkvw = (const float*)d_in[4];
  const float* wow  = (const float*)d_in[5];
  float* out = (float*)d_out;
  char* ws = (char*)d_ws;

  float*  modbuf  = (float*)(ws);                    // 131072 B
  ushort* hbuf    = (ushort*)(ws + 131072);          // 32 MB
  ushort* qkvw_b  = (ushort*)(ws + 33685504);        // 6 MB
  ushort* wow_b   = (ushort*)(ws + 39976960);        // 2 MB
  f16*    qbuf    = (f16*)(ws + 42074112);           // 32 MB
  f16*    kbuf    = (f16*)(ws + 75628544);           // 32 MB
  f16*    vtbuf   = (f16*)(ws + 109182976);          // 32 MB (V^T)
  ushort* abuf    = (ushort*)(ws + 142737408);       // 32 MB

  mod_gemm_kernel<<<dim3(2048), dim3(64), 0, stream>>>(t, mw, modbuf);
  rms_mod_kernel<<<dim3(16384), dim3(256), 0, stream>>>(x, nw, modbuf, hbuf);
  cvt_bf16_kernel<<<dim3(3072), dim3(256), 0, stream>>>(qkvw, qkvw_b, 786432);
  cvt_bf16_kernel<<<dim3(1024), dim3(256), 0, stream>>>(wow, wow_b, 262144);
  gemm_bt_kernel<3072, true><<<dim3(24, 128), dim3(256), 0, stream>>>(
      hbuf, qkvw_b, nullptr, qbuf, kbuf, vtbuf);
  rope_kernel<<<dim3(32768), dim3(256), 0, stream>>>(qbuf, kbuf);
  attn_kernel<<<dim3(8, 256), dim3(256), 0, stream>>>(qbuf, kbuf, vtbuf, abuf);
  gemm_bt_kernel<1024, false><<<dim3(8, 128), dim3(256), 0, stream>>>(
      abuf, wow_b, out, nullptr, nullptr, nullptr);
}